// Round 6
// baseline (188.407 us; speedup 1.0000x reference)
//
#include <hip/hip_runtime.h>
#include <math.h>

// Problem constants (fixed by reference)
#define BB    16384
#define RNN   256
#define LAT   64
#define ATTD  64
#define NA    32
#define HID   256
#define TBR   16       // rows per block -> grid 1024, 4 waves/block
#define KP    264      // bf16 K-stride for Sb (2-way bank alias = free)
#define RKP   72       // bf16 K-stride for rk/key tiles

// ws layout (float-unit offsets):
//   Wp   bf16[24][8][64][8] @ 0      GEMM1 B-operand, fragment-packed (coalesced loads)
//   VT   f32 [256][32]      @ 49152  VT[hc][a] = msg_b1[hc] + AL[a].w1_a[hc]
//   SV   f32 [256]          @ 57344  SumV[hc] = sum_a VT[hc][a]
//   W2p  bf16[2][8][64][8]  @ 57600  msg_w2 B-frag packed   (1024 pos = 4096 floats)
//   ALp  bf16[2][2][64][8]  @ 61696  AL B-frag packed       (256 pos = 1024 floats)
//   Qyp  bf16[2][2][64][8]  @ 62720  0.125*(AL@query_w.T+query_b) B-frag packed
#define WS_VT  49152
#define WS_SV  57344
#define WS_W2P 57600
#define WS_ALP 61696
#define WS_QYP 62720

typedef __attribute__((ext_vector_type(8))) short bf16x8;
typedef __attribute__((ext_vector_type(4))) float f32x4;
typedef __attribute__((ext_vector_type(8))) unsigned short ushort8;

__device__ __forceinline__ unsigned short f2bf(float x) {
    union { float f; unsigned u; } c; c.f = x;
    unsigned r = c.u + 0x7FFFu + ((c.u >> 16) & 1u);
    return (unsigned short)(r >> 16);
}

__device__ __forceinline__ bf16x8 pack_bf8(float4 v0, float4 v1) {
    union { ushort8 us; bf16x8 bf; } u;
    u.us[0] = f2bf(v0.x); u.us[1] = f2bf(v0.y); u.us[2] = f2bf(v0.z); u.us[3] = f2bf(v0.w);
    u.us[4] = f2bf(v1.x); u.us[5] = f2bf(v1.y); u.us[6] = f2bf(v1.z); u.us[7] = f2bf(v1.w);
    return u.bf;
}

__global__ __launch_bounds__(256) void prep_kernel(
    const float* __restrict__ AL,       // [32][64]
    const float* __restrict__ q_fc_w,   // [64][256]
    const float* __restrict__ msg_w1,   // [256][320]
    const float* __restrict__ msg_b1,   // [256]
    const float* __restrict__ msg_w2,   // [32][256]
    const float* __restrict__ key_w,    // [64][256]
    const float* __restrict__ query_w,  // [64][64]
    const float* __restrict__ query_b,  // [64]
    float* __restrict__ ws)
{
    const int tid = blockIdx.x * 256 + threadIdx.x;
    const int nth = gridDim.x * 256;
    unsigned short* Wp  = (unsigned short*)ws;
    float*          VT  = ws + WS_VT;
    float*          SV  = ws + WS_SV;
    unsigned short* W2p = (unsigned short*)(ws + WS_W2P);
    unsigned short* ALp = (unsigned short*)(ws + WS_ALP);
    unsigned short* Qyp = (unsigned short*)(ws + WS_QYP);

    // Wp: fragment-packed B for GEMM1. pos -> (g,kk,lane) -> 8 bf16
    for (int pos = tid; pos < 24 * 8 * 64; pos += nth) {
        const int lane = pos & 63, kkg = pos >> 6;
        const int kk = kkg & 7, g = kkg >> 3;
        const int ln = lane & 15, quad = lane >> 4;
        const int col = g * 16 + ln;
        const int k0  = kk * 32 + quad * 8;
        ushort8 u;
        #pragma unroll
        for (int j = 0; j < 8; ++j) {
            const int k = k0 + j;
            float v;
            if (col < 256)      v = msg_w1[col * 320 + k];
            else if (col < 320) v = q_fc_w[(col - 256) * 256 + k];
            else                v = key_w[(col - 320) * 256 + k];
            u[j] = f2bf(v);
        }
        *(ushort8*)(Wp + pos * 8) = u;
    }
    // VT[hc][a]
    for (int idx = tid; idx < HID * NA; idx += nth) {
        const int hc = idx >> 5, a = idx & 31;
        float s = msg_b1[hc];
        #pragma unroll 16
        for (int l = 0; l < LAT; ++l)
            s += AL[a * LAT + l] * msg_w1[hc * 320 + 256 + l];
        VT[idx] = s;
    }
    // SV[hc] = 32*msg_b1[hc] + sum_a sum_l AL[a][l]*w1_a[hc][l]
    for (int hc = tid; hc < HID; hc += nth) {
        float s = 32.f * msg_b1[hc];
        const float* w1a = msg_w1 + hc * 320 + 256;
        for (int a = 0; a < NA; ++a) {
            #pragma unroll 16
            for (int l = 0; l < LAT; ++l)
                s += AL[a * LAT + l] * w1a[l];
        }
        SV[hc] = s;
    }
    // W2p: B-frag packed msg_w2 (half = a-half)
    for (int pos = tid; pos < 2 * 8 * 64; pos += nth) {
        const int lane = pos & 63, kkh = pos >> 6;
        const int kk = kkh & 7, half = kkh >> 3;
        const int ln = lane & 15, quad = lane >> 4;
        const int a = half * 16 + ln, k0 = kk * 32 + quad * 8;
        ushort8 u;
        #pragma unroll
        for (int j = 0; j < 8; ++j) u[j] = f2bf(msg_w2[a * HID + k0 + j]);
        *(ushort8*)(W2p + pos * 8) = u;
    }
    // ALp
    for (int pos = tid; pos < 2 * 2 * 64; pos += nth) {
        const int lane = pos & 63, kkh = pos >> 6;
        const int kk = kkh & 1, half = kkh >> 1;
        const int ln = lane & 15, quad = lane >> 4;
        const int a = half * 16 + ln, k0 = kk * 32 + quad * 8;
        ushort8 u;
        #pragma unroll
        for (int j = 0; j < 8; ++j) u[j] = f2bf(AL[a * LAT + k0 + j]);
        *(ushort8*)(ALp + pos * 8) = u;
    }
    // Qyp[a][jj] = 0.125*(query_b[jj] + AL[a].query_w[jj]), B-frag packed
    for (int pos = tid; pos < 2 * 2 * 64; pos += nth) {
        const int lane = pos & 63, kkh = pos >> 6;
        const int kk = kkh & 1, half = kkh >> 1;
        const int ln = lane & 15, quad = lane >> 4;
        const int a = half * 16 + ln, k0 = kk * 32 + quad * 8;
        ushort8 u;
        #pragma unroll
        for (int j = 0; j < 8; ++j) {
            const int jj = k0 + j;
            float s = query_b[jj];
            #pragma unroll 16
            for (int l = 0; l < LAT; ++l)
                s += AL[a * LAT + l] * query_w[jj * LAT + l];
            u[j] = f2bf(0.125f * s);
        }
        *(ushort8*)(Qyp + pos * 8) = u;
    }
}

__global__ __launch_bounds__(256, 4) void main_kernel(
    const float* __restrict__ h,        // [16384][256]
    const float* __restrict__ q_fc_b,   // [64]
    const float* __restrict__ msg_b2,   // [32]
    const float* __restrict__ key_b,    // [64]
    const float* __restrict__ ws,
    float* __restrict__ out)            // [16384][32]
{
    __shared__ unsigned short Sb[TBR * KP];     // 8448 B
    __shared__ unsigned short rkb[TBR * RKP];   // 2304 B
    __shared__ unsigned short keyb[TBR * RKP];  // 2304 B
    __shared__ float Scl[TBR * 33];             // 2112 B
    __shared__ float ql[TBR * 33];              // 2112 B
    // total ~17.3 KB (hbuf eliminated: A-frags load direct from global)

    const int t  = threadIdx.x;
    const int b0 = blockIdx.x * TBR;
    const short* Wps  = (const short*)ws;
    const float* VTf  = ws + WS_VT;
    const float* SVf  = ws + WS_SV;
    const short* W2ps = (const short*)(ws + WS_W2P);
    const short* ALps = (const short*)(ws + WS_ALP);
    const short* Qyps = (const short*)(ws + WS_QYP);

    const int lane = t & 63, w = t >> 6;
    const int ln = lane & 15, quad = lane >> 4;

    // ---- A-fragments direct from global: row b0+ln, k = kk*32 + quad*8 + j ----
    bf16x8 af[8];
    {
        const float* hrow = h + (size_t)(b0 + ln) * RNN + quad * 8;
        #pragma unroll
        for (int kk = 0; kk < 8; ++kk) {
            const float4 v0 = *(const float4*)(hrow + kk * 32);
            const float4 v1 = *(const float4*)(hrow + kk * 32 + 4);
            af[kk] = pack_bf8(v0, v1);
        }
    }

    // ---- GEMM1 + fused post, round-robin groups: g = w + gi*4 ----
    // gi 0..3 -> S-columns, gi 4 -> role_key, gi 5 -> key. Wave-balanced.
    #pragma unroll
    for (int gi = 0; gi < 6; ++gi) {
        const int g   = w + gi * 4;
        const int col = g * 16 + ln;
        const short* bp = Wps + (size_t)g * 4096 + lane * 8;

        float vt[32];
        float c1 = 0.f;
        if (gi < 4) {
            const float4* vp = (const float4*)(VTf + col * NA);
            #pragma unroll
            for (int i = 0; i < 8; ++i) {
                const float4 v = vp[i];
                vt[4*i] = v.x; vt[4*i+1] = v.y; vt[4*i+2] = v.z; vt[4*i+3] = v.w;
            }
            c1 = 0.505f * SVf[col];
        }

        f32x4 acc = (f32x4){0.f, 0.f, 0.f, 0.f};
        #pragma unroll
        for (int kk = 0; kk < 8; ++kk) {
            const bf16x8 bfr = *(const bf16x8*)(bp + kk * 512);
            acc = __builtin_amdgcn_mfma_f32_16x16x32_bf16(af[kk], bfr, acc, 0, 0, 0);
        }

        if (gi < 4) {
            // S = 0.505*(32u + SumV) + 0.495*sum_a |u + v_a|   (leaky identity)
            #pragma unroll
            for (int r = 0; r < 4; ++r) {
                const float u = acc[r];
                float s0 = 0.f, s1 = 0.f;
                #pragma unroll
                for (int a = 0; a < 32; a += 2) {
                    s0 += __builtin_fabsf(u + vt[a]);
                    s1 += __builtin_fabsf(u + vt[a + 1]);
                }
                const float S = fmaf(16.16f, u, c1) + 0.495f * (s0 + s1);
                Sb[(quad * 4 + r) * KP + col] = f2bf(S);
            }
        } else if (gi == 4) {
            const int k = col - 256;
            const float bias = q_fc_b[k];
            #pragma unroll
            for (int r = 0; r < 4; ++r)
                rkb[(quad * 4 + r) * RKP + k] = f2bf(acc[r] + bias);
        } else {
            const int k = col - 320;
            const float bias = key_b[k];
            #pragma unroll
            for (int r = 0; r < 4; ++r)
                keyb[(quad * 4 + r) * RKP + k] = f2bf(acc[r] + bias);
        }
    }
    __syncthreads();   // barrier 1: S/rk/key tiles complete

    // ---- round 2: one MFMA job per wave ----
    f32x4 mc = (f32x4){0.f, 0.f, 0.f, 0.f};
    if (w < 2) {
        // msgsum half w: S[16][256] @ w2^T
        const short* Sbs = (const short*)Sb;
        #pragma unroll
        for (int kk = 0; kk < 8; ++kk) {
            const bf16x8 afr = *(const bf16x8*)(Sbs + ln * KP + kk * 32 + quad * 8);
            const bf16x8 bfr = *(const bf16x8*)(W2ps + ((w * 8 + kk) * 64 + lane) * 8);
            mc = __builtin_amdgcn_mfma_f32_16x16x32_bf16(afr, bfr, mc, 0, 0, 0);
        }
    } else if (w == 2) {
        // q = role_key @ AL^T (both a-halves)
        const short* rks = (const short*)rkb;
        #pragma unroll
        for (int half = 0; half < 2; ++half) {
            f32x4 qc = (f32x4){0.f, 0.f, 0.f, 0.f};
            #pragma unroll
            for (int kk = 0; kk < 2; ++kk) {
                const bf16x8 aq = *(const bf16x8*)(rks + ln * RKP + kk * 32 + quad * 8);
                const bf16x8 bq = *(const bf16x8*)(ALps + ((half * 2 + kk) * 64 + lane) * 8);
                qc = __builtin_amdgcn_mfma_f32_16x16x32_bf16(aq, bq, qc, 0, 0, 0);
            }
            #pragma unroll
            for (int r = 0; r < 4; ++r)
                ql[(quad * 4 + r) * 33 + half * 16 + ln] = qc[r];
        }
    } else {
        // scores = key @ (Qy/8)^T (both a-halves)
        const short* kys = (const short*)keyb;
        #pragma unroll
        for (int half = 0; half < 2; ++half) {
            f32x4 sc = (f32x4){0.f, 0.f, 0.f, 0.f};
            #pragma unroll
            for (int kk = 0; kk < 2; ++kk) {
                const bf16x8 ak = *(const bf16x8*)(kys + ln * RKP + kk * 32 + quad * 8);
                const bf16x8 bk = *(const bf16x8*)(Qyps + ((half * 2 + kk) * 64 + lane) * 8);
                sc = __builtin_amdgcn_mfma_f32_16x16x32_bf16(ak, bk, sc, 0, 0, 0);
            }
            #pragma unroll
            for (int r = 0; r < 4; ++r)
                Scl[(quad * 4 + r) * 33 + half * 16 + ln] = sc[r];
        }
    }
    __syncthreads();   // barrier 2 (last): Scl/ql complete

    // ---- waves 0,1: in-wave softmax stats + combine + store (no more barriers) ----
    if (w < 2) {
        // each lane computes stats for row = ln (lanes 16+ are harmless duplicates);
        // Scl reads are 4-way same-address broadcast -> conflict-free
        const float* srow = Scl + ln * 33;
        float mx = -1e30f;
        #pragma unroll
        for (int i = 0; i < NA; ++i) mx = fmaxf(mx, srow[i]);
        float den = 0.f;
        #pragma unroll
        for (int i = 0; i < NA; ++i) den += __expf(srow[i] - mx);
        const float rd = 1.f / den;

        const int a = w * 16 + ln;
        const float b2 = 32.f * msg_b2[a];
        #pragma unroll
        for (int r = 0; r < 4; ++r) {
            const int row = quad * 4 + r;
            const float mxr = __shfl(mx, row);
            const float rdr = __shfl(rd, row);
            const float sm = __expf(Scl[row * 33 + a] - mxr) * rdr;
            out[(size_t)(b0 + row) * NA + a] = ql[row * 33 + a] + sm * (mc[r] + b2);
        }
    }
}

extern "C" void kernel_launch(void* const* d_in, const int* in_sizes, int n_in,
                              void* d_out, int out_size, void* d_ws, size_t ws_size,
                              hipStream_t stream) {
    const float* h        = (const float*)d_in[0];
    const float* AL       = (const float*)d_in[1];
    const float* q_fc_w   = (const float*)d_in[2];
    const float* q_fc_b   = (const float*)d_in[3];
    const float* msg_w1   = (const float*)d_in[4];
    const float* msg_b1   = (const float*)d_in[5];
    const float* msg_w2   = (const float*)d_in[6];
    const float* msg_b2   = (const float*)d_in[7];
    const float* key_w    = (const float*)d_in[8];
    const float* key_b    = (const float*)d_in[9];
    const float* query_w  = (const float*)d_in[10];
    const float* query_b  = (const float*)d_in[11];
    float* out = (float*)d_out;
    float* ws  = (float*)d_ws;

    prep_kernel<<<128, 256, 0, stream>>>(AL, q_fc_w, msg_w1, msg_b1, msg_w2,
                                         key_w, query_w, query_b, ws);
    main_kernel<<<BB / TBR, 256, 0, stream>>>(h, q_fc_b, msg_b2, key_b, ws, out);
}

// Round 7
// 122.411 us; speedup vs baseline: 1.5391x; 1.5391x over previous
//
#include <hip/hip_runtime.h>
#include <math.h>

// Problem constants (fixed by reference)
#define BB    16384
#define RNN   256
#define LAT   64
#define ATTD  64
#define NA    32
#define HID   256
#define TBR   16       // rows per block -> grid 1024, 4 waves/block
#define KP    264      // bf16 K-stride for Sb (2-way bank alias = free)
#define RKP   72       // bf16 K-stride for rk/key tiles

// ws layout (float-unit offsets):
//   Wp   bf16[24][8][64][8] @ 0      GEMM1 B-operand, fragment-packed (coalesced loads)
//   VT   f32 [256][32]      @ 49152  VT[hc][a] = msg_b1[hc] + AL[a].w1_a[hc]
//   SV   f32 [256]          @ 57344  SumV[hc] = sum_a VT[hc][a]
//   W2p  bf16[2][8][64][8]  @ 57600  msg_w2 B-frag packed   (1024 pos = 4096 floats)
//   ALp  bf16[2][2][64][8]  @ 61696  AL B-frag packed       (256 pos = 1024 floats)
//   Qyp  bf16[2][2][64][8]  @ 62720  0.125*(AL@query_w.T+query_b) B-frag packed
#define WS_VT  49152
#define WS_SV  57344
#define WS_W2P 57600
#define WS_ALP 61696
#define WS_QYP 62720

typedef __attribute__((ext_vector_type(8))) short bf16x8;
typedef __attribute__((ext_vector_type(4))) float f32x4;
typedef __attribute__((ext_vector_type(8))) unsigned short ushort8;

__device__ __forceinline__ unsigned short f2bf(float x) {
    union { float f; unsigned u; } c; c.f = x;
    unsigned r = c.u + 0x7FFFu + ((c.u >> 16) & 1u);
    return (unsigned short)(r >> 16);
}

__device__ __forceinline__ bf16x8 pack_bf8(float4 v0, float4 v1) {
    union { ushort8 us; bf16x8 bf; } u;
    u.us[0] = f2bf(v0.x); u.us[1] = f2bf(v0.y); u.us[2] = f2bf(v0.z); u.us[3] = f2bf(v0.w);
    u.us[4] = f2bf(v1.x); u.us[5] = f2bf(v1.y); u.us[6] = f2bf(v1.z); u.us[7] = f2bf(v1.w);
    return u.bf;
}

__device__ __forceinline__ float dot4(float4 a, float4 b) {
    return a.x * b.x + a.y * b.y + a.z * b.z + a.w * b.w;
}

// R6 lesson: every prep loop used `pos = tid` ranges < 12288, so blocks 48+
// idled and block 0 ran all jobs serially (80 us, Occupancy 0.2%). Now each
// job owns a disjoint blockIdx range -> all jobs run concurrently on
// different CUs; SV's serial chain replaced with LDS-staged ALsum.
__global__ __launch_bounds__(256) void prep_kernel(
    const float* __restrict__ AL,       // [32][64]
    const float* __restrict__ q_fc_w,   // [64][256]
    const float* __restrict__ msg_w1,   // [256][320]
    const float* __restrict__ msg_b1,   // [256]
    const float* __restrict__ msg_w2,   // [32][256]
    const float* __restrict__ key_w,    // [64][256]
    const float* __restrict__ query_w,  // [64][64]
    const float* __restrict__ query_b,  // [64]
    float* __restrict__ ws)
{
    __shared__ float alsum[64];         // used by the SV block only
    const int blk = blockIdx.x;
    const int t   = threadIdx.x;

    unsigned short* Wp  = (unsigned short*)ws;
    float*          VT  = ws + WS_VT;
    float*          SV  = ws + WS_SV;
    unsigned short* W2p = (unsigned short*)(ws + WS_W2P);
    unsigned short* ALp = (unsigned short*)(ws + WS_ALP);
    unsigned short* Qyp = (unsigned short*)(ws + WS_QYP);

    if (blk < 48) {
        // ---- Wp: fragment-packed GEMM1 B-operand; pos in [0,12288) ----
        const int pos = blk * 256 + t;
        const int lane = pos & 63, kkg = pos >> 6;
        const int kk = kkg & 7, g = kkg >> 3;
        const int ln = lane & 15, quad = lane >> 4;
        const int col = g * 16 + ln;
        const int k0  = kk * 32 + quad * 8;
        const float* src;
        if (col < 256)      src = msg_w1 + col * 320 + k0;
        else if (col < 320) src = q_fc_w + (col - 256) * 256 + k0;
        else                src = key_w + (col - 320) * 256 + k0;
        const float4 v0 = *(const float4*)src;
        const float4 v1 = *(const float4*)(src + 4);
        union { ushort8 us; bf16x8 bf; } u;
        u.bf = pack_bf8(v0, v1);
        *(ushort8*)(Wp + pos * 8) = u.us;
    } else if (blk < 80) {
        // ---- VT[hc][a]; idx in [0,8192) ----
        const int idx = (blk - 48) * 256 + t;
        const int hc = idx >> 5, a = idx & 31;
        const float4* alp = (const float4*)(AL + a * LAT);
        const float4* w1p = (const float4*)(msg_w1 + hc * 320 + 256);
        float s = msg_b1[hc];
        #pragma unroll
        for (int i = 0; i < 16; ++i) s += dot4(alp[i], w1p[i]);
        VT[idx] = s;
    } else if (blk == 80) {
        // ---- SV[hc] = 32*b1[hc] + sum_l (sum_a AL[a][l]) * w1a[hc][l] ----
        if (t < 64) {
            float s = 0.f;
            #pragma unroll 8
            for (int a = 0; a < NA; ++a) s += AL[a * LAT + t];
            alsum[t] = s;
        }
        __syncthreads();
        {
            float s = 32.f * msg_b1[t];
            const float* w1a = msg_w1 + t * 320 + 256;
            #pragma unroll 16
            for (int l = 0; l < LAT; ++l) s += alsum[l] * w1a[l];
            SV[t] = s;
        }
    } else if (blk < 85) {
        // ---- W2p: B-frag packed msg_w2; pos in [0,1024) ----
        const int pos = (blk - 81) * 256 + t;
        const int lane = pos & 63, kkh = pos >> 6;
        const int kk = kkh & 7, half = kkh >> 3;
        const int ln = lane & 15, quad = lane >> 4;
        const int a = half * 16 + ln, k0 = kk * 32 + quad * 8;
        const float4 v0 = *(const float4*)(msg_w2 + a * HID + k0);
        const float4 v1 = *(const float4*)(msg_w2 + a * HID + k0 + 4);
        union { ushort8 us; bf16x8 bf; } u;
        u.bf = pack_bf8(v0, v1);
        *(ushort8*)(W2p + pos * 8) = u.us;
    } else if (blk == 85) {
        // ---- ALp: pos in [0,256) ----
        const int pos = t;
        const int lane = pos & 63, kkh = pos >> 6;
        const int kk = kkh & 1, half = kkh >> 1;
        const int ln = lane & 15, quad = lane >> 4;
        const int a = half * 16 + ln, k0 = kk * 32 + quad * 8;
        const float4 v0 = *(const float4*)(AL + a * LAT + k0);
        const float4 v1 = *(const float4*)(AL + a * LAT + k0 + 4);
        union { ushort8 us; bf16x8 bf; } u;
        u.bf = pack_bf8(v0, v1);
        *(ushort8*)(ALp + pos * 8) = u.us;
    } else {
        // ---- Qyp[a][jj] = 0.125*(query_b[jj] + AL[a].query_w[jj]); pos in [0,256) ----
        const int pos = t;
        const int lane = pos & 63, kkh = pos >> 6;
        const int kk = kkh & 1, half = kkh >> 1;
        const int ln = lane & 15, quad = lane >> 4;
        const int a = half * 16 + ln, k0 = kk * 32 + quad * 8;
        const float4* alp = (const float4*)(AL + a * LAT);
        ushort8 u;
        #pragma unroll
        for (int j = 0; j < 8; ++j) {
            const int jj = k0 + j;
            const float4* qwp = (const float4*)(query_w + jj * LAT);
            float s = query_b[jj];
            #pragma unroll
            for (int i = 0; i < 16; ++i) s += dot4(alp[i], qwp[i]);
            u[j] = f2bf(0.125f * s);
        }
        *(ushort8*)(Qyp + pos * 8) = u;
    }
}

__global__ __launch_bounds__(256, 4) void main_kernel(
    const float* __restrict__ h,        // [16384][256]
    const float* __restrict__ q_fc_b,   // [64]
    const float* __restrict__ msg_b2,   // [32]
    const float* __restrict__ key_b,    // [64]
    const float* __restrict__ ws,
    float* __restrict__ out)            // [16384][32]
{
    __shared__ unsigned short Sb[TBR * KP];     // 8448 B
    __shared__ unsigned short rkb[TBR * RKP];   // 2304 B
    __shared__ unsigned short keyb[TBR * RKP];  // 2304 B
    __shared__ float Scl[TBR * 33];             // 2112 B
    __shared__ float ql[TBR * 33];              // 2112 B
    // total ~17.3 KB (hbuf eliminated: A-frags load direct from global)

    const int t  = threadIdx.x;
    const int b0 = blockIdx.x * TBR;
    const short* Wps  = (const short*)ws;
    const float* VTf  = ws + WS_VT;
    const float* SVf  = ws + WS_SV;
    const short* W2ps = (const short*)(ws + WS_W2P);
    const short* ALps = (const short*)(ws + WS_ALP);
    const short* Qyps = (const short*)(ws + WS_QYP);

    const int lane = t & 63, w = t >> 6;
    const int ln = lane & 15, quad = lane >> 4;

    // ---- A-fragments direct from global: row b0+ln, k = kk*32 + quad*8 + j ----
    bf16x8 af[8];
    {
        const float* hrow = h + (size_t)(b0 + ln) * RNN + quad * 8;
        #pragma unroll
        for (int kk = 0; kk < 8; ++kk) {
            const float4 v0 = *(const float4*)(hrow + kk * 32);
            const float4 v1 = *(const float4*)(hrow + kk * 32 + 4);
            af[kk] = pack_bf8(v0, v1);
        }
    }

    // ---- GEMM1 + fused post, round-robin groups: g = w + gi*4 ----
    // gi 0..3 -> S-columns, gi 4 -> role_key, gi 5 -> key. Wave-balanced.
    #pragma unroll
    for (int gi = 0; gi < 6; ++gi) {
        const int g   = w + gi * 4;
        const int col = g * 16 + ln;
        const short* bp = Wps + (size_t)g * 4096 + lane * 8;

        float vt[32];
        float c1 = 0.f;
        if (gi < 4) {
            const float4* vp = (const float4*)(VTf + col * NA);
            #pragma unroll
            for (int i = 0; i < 8; ++i) {
                const float4 v = vp[i];
                vt[4*i] = v.x; vt[4*i+1] = v.y; vt[4*i+2] = v.z; vt[4*i+3] = v.w;
            }
            c1 = 0.505f * SVf[col];
        }

        f32x4 acc = (f32x4){0.f, 0.f, 0.f, 0.f};
        #pragma unroll
        for (int kk = 0; kk < 8; ++kk) {
            const bf16x8 bfr = *(const bf16x8*)(bp + kk * 512);
            acc = __builtin_amdgcn_mfma_f32_16x16x32_bf16(af[kk], bfr, acc, 0, 0, 0);
        }

        if (gi < 4) {
            // S = 0.505*(32u + SumV) + 0.495*sum_a |u + v_a|   (leaky identity)
            #pragma unroll
            for (int r = 0; r < 4; ++r) {
                const float u = acc[r];
                float s0 = 0.f, s1 = 0.f;
                #pragma unroll
                for (int a = 0; a < 32; a += 2) {
                    s0 += __builtin_fabsf(u + vt[a]);
                    s1 += __builtin_fabsf(u + vt[a + 1]);
                }
                const float S = fmaf(16.16f, u, c1) + 0.495f * (s0 + s1);
                Sb[(quad * 4 + r) * KP + col] = f2bf(S);
            }
        } else if (gi == 4) {
            const int k = col - 256;
            const float bias = q_fc_b[k];
            #pragma unroll
            for (int r = 0; r < 4; ++r)
                rkb[(quad * 4 + r) * RKP + k] = f2bf(acc[r] + bias);
        } else {
            const int k = col - 320;
            const float bias = key_b[k];
            #pragma unroll
            for (int r = 0; r < 4; ++r)
                keyb[(quad * 4 + r) * RKP + k] = f2bf(acc[r] + bias);
        }
    }
    __syncthreads();   // barrier 1: S/rk/key tiles complete

    // ---- round 2: one MFMA job per wave ----
    f32x4 mc = (f32x4){0.f, 0.f, 0.f, 0.f};
    if (w < 2) {
        // msgsum half w: S[16][256] @ w2^T
        const short* Sbs = (const short*)Sb;
        #pragma unroll
        for (int kk = 0; kk < 8; ++kk) {
            const bf16x8 afr = *(const bf16x8*)(Sbs + ln * KP + kk * 32 + quad * 8);
            const bf16x8 bfr = *(const bf16x8*)(W2ps + ((w * 8 + kk) * 64 + lane) * 8);
            mc = __builtin_amdgcn_mfma_f32_16x16x32_bf16(afr, bfr, mc, 0, 0, 0);
        }
    } else if (w == 2) {
        // q = role_key @ AL^T (both a-halves)
        const short* rks = (const short*)rkb;
        #pragma unroll
        for (int half = 0; half < 2; ++half) {
            f32x4 qc = (f32x4){0.f, 0.f, 0.f, 0.f};
            #pragma unroll
            for (int kk = 0; kk < 2; ++kk) {
                const bf16x8 aq = *(const bf16x8*)(rks + ln * RKP + kk * 32 + quad * 8);
                const bf16x8 bq = *(const bf16x8*)(ALps + ((half * 2 + kk) * 64 + lane) * 8);
                qc = __builtin_amdgcn_mfma_f32_16x16x32_bf16(aq, bq, qc, 0, 0, 0);
            }
            #pragma unroll
            for (int r = 0; r < 4; ++r)
                ql[(quad * 4 + r) * 33 + half * 16 + ln] = qc[r];
        }
    } else {
        // scores = key @ (Qy/8)^T (both a-halves)
        const short* kys = (const short*)keyb;
        #pragma unroll
        for (int half = 0; half < 2; ++half) {
            f32x4 sc = (f32x4){0.f, 0.f, 0.f, 0.f};
            #pragma unroll
            for (int kk = 0; kk < 2; ++kk) {
                const bf16x8 ak = *(const bf16x8*)(kys + ln * RKP + kk * 32 + quad * 8);
                const bf16x8 bk = *(const bf16x8*)(Qyps + ((half * 2 + kk) * 64 + lane) * 8);
                sc = __builtin_amdgcn_mfma_f32_16x16x32_bf16(ak, bk, sc, 0, 0, 0);
            }
            #pragma unroll
            for (int r = 0; r < 4; ++r)
                Scl[(quad * 4 + r) * 33 + half * 16 + ln] = sc[r];
        }
    }
    __syncthreads();   // barrier 2 (last): Scl/ql complete

    // ---- waves 0,1: in-wave softmax stats + combine + store (no more barriers) ----
    if (w < 2) {
        // each lane computes stats for row = ln (lanes 16+ are harmless duplicates);
        // Scl reads are 4-way same-address broadcast -> conflict-free
        const float* srow = Scl + ln * 33;
        float mx = -1e30f;
        #pragma unroll
        for (int i = 0; i < NA; ++i) mx = fmaxf(mx, srow[i]);
        float den = 0.f;
        #pragma unroll
        for (int i = 0; i < NA; ++i) den += __expf(srow[i] - mx);
        const float rd = 1.f / den;

        const int a = w * 16 + ln;
        const float b2 = 32.f * msg_b2[a];
        #pragma unroll
        for (int r = 0; r < 4; ++r) {
            const int row = quad * 4 + r;
            const float mxr = __shfl(mx, row);
            const float rdr = __shfl(rd, row);
            const float sm = __expf(Scl[row * 33 + a] - mxr) * rdr;
            out[(size_t)(b0 + row) * NA + a] = ql[row * 33 + a] + sm * (mc[r] + b2);
        }
    }
}

extern "C" void kernel_launch(void* const* d_in, const int* in_sizes, int n_in,
                              void* d_out, int out_size, void* d_ws, size_t ws_size,
                              hipStream_t stream) {
    const float* h        = (const float*)d_in[0];
    const float* AL       = (const float*)d_in[1];
    const float* q_fc_w   = (const float*)d_in[2];
    const float* q_fc_b   = (const float*)d_in[3];
    const float* msg_w1   = (const float*)d_in[4];
    const float* msg_b1   = (const float*)d_in[5];
    const float* msg_w2   = (const float*)d_in[6];
    const float* msg_b2   = (const float*)d_in[7];
    const float* key_w    = (const float*)d_in[8];
    const float* key_b    = (const float*)d_in[9];
    const float* query_w  = (const float*)d_in[10];
    const float* query_b  = (const float*)d_in[11];
    float* out = (float*)d_out;
    float* ws  = (float*)d_ws;

    prep_kernel<<<87, 256, 0, stream>>>(AL, q_fc_w, msg_w1, msg_b1, msg_w2,
                                        key_w, query_w, query_b, ws);
    main_kernel<<<BB / TBR, 256, 0, stream>>>(h, q_fc_b, msg_b2, key_b, ws, out);
}